// Round 8
// baseline (333.974 us; speedup 1.0000x reference)
//
#include <hip/hip_runtime.h>
#include <hip/hip_bf16.h>
#include <stdint.h>

// ---------------------------------------------------------------------------
// AstrocyteMemoryModule r15: 9 launches.
//  L1 prep-A: inpj+x cvt, W^T (q,k,v), combined bias, accum bias-init,
//      O/l zero (~57 MB traffic)
//  L2' gemm_bigc: Wc = Wi@W (192 GEMM blocks, grid-FIRST) + 3328 cvt blocks
//      riding the idle CUs/memory pipes.
//  L3 gemm256 (best measured L3 @60-62us): 256^2 phase-split 1/CU pipeline
//      + thin qh blocks at grid tail.
//  L4 flash r2: 512 blocks (16h x 32c of 256 keys) = 2 blocks/CU
//      co-resident = 2 waves/SIMD. Was 256 blocks = 1 wave/SIMD with a
//      serial load->MFMA->exp->LDS->MFMA chain = zero latency hiding; the
//      invisible ~50us elephant (never in top-5, cutoffs 60-68).
//  L5-L9 tail stages: split-K atomic GEMMs.
// ---------------------------------------------------------------------------

typedef __bf16 bf16;
typedef __bf16 bf16x4 __attribute__((ext_vector_type(4)));
typedef __bf16 bf16x8 __attribute__((ext_vector_type(8)));
typedef float f32x4 __attribute__((ext_vector_type(4)));

#define D_ 1024
#define M_ 8192
#define B_ 64
#define H_ 16

static __device__ __forceinline__ void gload16(const void* g, void* l) {
  __builtin_amdgcn_global_load_lds(
      (const __attribute__((address_space(1))) void*)g,
      (__attribute__((address_space(3))) void*)l, 16, 0, 0);
}

static __device__ __forceinline__ f32x4 mfma16(bf16x8 a, bf16x8 b, f32x4 c) {
  return __builtin_amdgcn_mfma_f32_16x16x32_bf16(a, b, c, 0, 0, 0);
}

// ----------------- 128B/thread block-uniform cvt helper --------------------
struct CvtD { const float* src; bf16* dst; int end; };  // end in BLOCK units

template <int N>
static __device__ __forceinline__ void cvt_block(const CvtD* d, int b, int tid) {
  CvtD dd = d[N - 1];
  int begin = N > 1 ? d[N - 2].end : 0;
#pragma unroll
  for (int t = N - 2; t >= 0; t--)
    if (b < d[t].end) { dd = d[t]; begin = t ? d[t - 1].end : 0; }
  int64_t i = (int64_t)(b - begin) * 8192 + tid * 32;
  const float* src = dd.src + i;
  bf16* dst = dd.dst + i;
  float4 v[8];
#pragma unroll
  for (int u = 0; u < 8; u++) v[u] = *(const float4*)(src + u * 4);
#pragma unroll
  for (int u = 0; u < 8; u++) {
    bf16x4 o = { (bf16)v[u].x, (bf16)v[u].y, (bf16)v[u].z, (bf16)v[u].w };
    *(bf16x4*)(dst + u * 4) = o;
  }
}

// ---------------- thin GEMM (M=64): C = A @ B^T, reg-prefetched -------------
template <int U, int KLEN, typename OutT>
__device__ __forceinline__ void thin_gemm(
    const bf16* __restrict__ A, int lda,
    const bf16* __restrict__ Bm, int ldb,
    OutT* __restrict__ C, int ldc,
    const float* __restrict__ bias, float scale) {
  const int tid = threadIdx.x, lane = tid & 63, w = tid >> 6;
  const int rl = lane & 15, qq = lane >> 4;
  const bf16* pa = A + (int64_t)(w * 16 + rl) * lda + qq * 8;
  const bf16* pb[4];
  pb[0] = Bm + (int64_t)rl * ldb + qq * 8;
  pb[1] = pb[0] + (int64_t)16 * ldb;
  pb[2] = pb[0] + (int64_t)32 * ldb;
  pb[3] = pb[0] + (int64_t)48 * ldb;
  f32x4 acc[4] = {};
  bf16x8 av[2][U], bv[2][U][4];
#pragma unroll
  for (int u = 0; u < U; u++) {
    av[0][u] = *(const bf16x8*)(pa + u * 32);
#pragma unroll
    for (int j = 0; j < 4; j++)
      bv[0][u][j] = *(const bf16x8*)(pb[j] + u * 32);
  }
  constexpr int NI = KLEN / (32 * U);
#pragma unroll
  for (int it = 0; it < NI; it++) {
    const int cur = it & 1, nxt = cur ^ 1;
    if (it + 1 < NI) {
      int k = (it + 1) * 32 * U;
#pragma unroll
      for (int u = 0; u < U; u++) {
        av[nxt][u] = *(const bf16x8*)(pa + k + u * 32);
#pragma unroll
        for (int j = 0; j < 4; j++)
          bv[nxt][u][j] = *(const bf16x8*)(pb[j] + k + u * 32);
      }
    }
#pragma unroll
    for (int u = 0; u < U; u++)
#pragma unroll
      for (int j = 0; j < 4; j++)
        acc[j] = mfma16(av[cur][u], bv[cur][u][j], acc[j]);
  }
#pragma unroll
  for (int j = 0; j < 4; j++) {
    int gn = j * 16 + rl;
    float bb = bias ? bias[gn] : 0.0f;
#pragma unroll
    for (int r = 0; r < 4; r++) {
      int gm = w * 16 + qq * 4 + r;
      C[(int64_t)gm * ldc + gn] = (OutT)((acc[j][r] + bb) * scale);
    }
  }
}

// ----------------------------- prep-A (L1) ---------------------------------
// blocks: [0,392) cvt (inpj 384, xbf 8), [392,3464) W^T (q,k,v),
//         [3464,4232) bias-combine, [4232,4616) accum bias-init,
//         [4616,4680) O/l zero
struct PrepArgs {
  CvtD d[2];
  const float *Wq, *Wk, *Wv, *inw, *inb, *bq, *bk, *bv;
  const float *outb, *gb1, *gb2, *ib1, *ib2;
  bf16* WT;
  float *bc, *msR, *g1R, *gateR, *h1R, *out, *Oraw, *lmat;
};

__global__ __launch_bounds__(256) void prep_kernel(PrepArgs a) {
  const int bx = blockIdx.x, tid = threadIdx.x;
  if (bx < 392) {
    cvt_block<2>(a.d, bx, tid);
  } else if (bx < 3464) {
    int t = bx - 392;
    int z = t >> 10, rem = t & 1023;   // z: 0=Wq 1=Wk 2=Wv
    const float* src = z == 0 ? a.Wq : z == 1 ? a.Wk : a.Wv;
    bf16* out = a.WT + (int64_t)z * D_ * D_;
    __shared__ bf16 tile[32][33];
    int tx = tid & 31, ty = tid >> 5;
    int r0 = (rem >> 5) * 32, c0 = (rem & 31) * 32;
#pragma unroll
    for (int i = 0; i < 32; i += 8)
      tile[ty + i][tx] = (bf16)src[(int64_t)(r0 + ty + i) * D_ + c0 + tx];
    __syncthreads();
#pragma unroll
    for (int i = 0; i < 32; i += 8)
      out[(int64_t)(c0 + ty + i) * D_ + r0 + tx] = tile[tx][ty + i];
  } else if (bx < 4232) {
    int t = bx - 3464;
    int w = tid >> 6, lane = tid & 63;
    int ng = t * 4 + w;  // [0, 3072)
    int z = ng >> 10;
    const float* Wi = a.inw + (int64_t)ng * D_;
    const float* b = z == 0 ? a.bq : z == 1 ? a.bk : a.bv;
    float acc = 0.f;
#pragma unroll
    for (int l = 0; l < D_; l += 64) acc += Wi[l + lane] * b[l + lane];
#pragma unroll
    for (int m = 32; m; m >>= 1) acc += __shfl_xor(acc, m, 64);
    if (lane == 0) a.bc[ng] = acc + a.inb[ng];
  } else if (bx < 4616) {
    int t = bx - 4232;            // [0, 384)
    int seg = t >> 6, row = t & 63;
    int n = tid * 4;              // [0, 1024)
    const float* b;
    float* dst;
    int bn = n;
    if (seg == 0)      { dst = a.msR   + row * 1024;        b = a.outb; }
    else if (seg == 1) { dst = a.g1R   + row * 1024;        b = a.gb1;  }
    else if (seg == 2) { dst = a.gateR + row * 1024;        b = a.gb2;  }
    else if (seg == 3) { dst = a.h1R   + row * 2048;        b = a.ib1;  }
    else if (seg == 4) { dst = a.h1R   + row * 2048 + 1024; b = a.ib1; bn = 1024 + n; }
    else               { dst = a.out   + row * 1024;        b = a.ib2;  }
    *(float4*)(dst + n) = *(const float4*)(b + bn);
  } else {
    int b = bx - 4616;            // [0, 64): O/l zero
    float4 z4 = {0.f, 0.f, 0.f, 0.f};
    *(float4*)(a.Oraw + b * 1024 + tid * 4) = z4;
    if (b < 16 && tid < 64) a.lmat[b * 64 + tid] = 0.f;
  }
}

// ------------- L2': Wc GEMM (192 blocks) + bulk cvt (3328 blocks) ----------
struct L2Args { CvtD d[7]; };

__global__ __launch_bounds__(256) void gemm_bigc(
    const bf16* __restrict__ A, const bf16* __restrict__ Bm,
    bf16* __restrict__ C, L2Args ca) {
  const int bid = blockIdx.x, tid = threadIdx.x;
  if (bid >= 192) {
    cvt_block<7>(ca.d, bid - 192, tid);
    return;
  }
  const int z = bid >> 6, r = bid & 63;
  const int m0 = (r >> 3) * 128, n0 = (r & 7) * 128;
  A += (int64_t)z * D_ * D_; Bm += (int64_t)z * D_ * D_;
  __shared__ alignas(16) bf16 As[128 * 32];
  __shared__ alignas(16) bf16 Bs[128 * 32];
  const int lane = tid & 63, w = tid >> 6;
  const int wm = (w & 1) * 64, wn = (w >> 1) * 64;
  const int rl = lane & 15, qq = lane >> 4;
  f32x4 acc[4][4] = {};

  int c0 = w * 64 + lane, c1 = (4 + w) * 64 + lane;
  int ra0 = c0 >> 2, qa0 = (c0 & 3) ^ ((ra0 >> 1) & 3);
  int ra1 = c1 >> 2, qa1 = (c1 & 3) ^ ((ra1 >> 1) & 3);
  const bf16* gA0 = A + (int64_t)(m0 + ra0) * D_ + qa0 * 8;
  const bf16* gA1 = A + (int64_t)(m0 + ra1) * D_ + qa1 * 8;
  const bf16* gB0 = Bm + (int64_t)(n0 + ra0) * D_ + qa0 * 8;
  const bf16* gB1 = Bm + (int64_t)(n0 + ra1) * D_ + qa1 * 8;
  bf16* lA0 = As + w * 512;
  bf16* lA1 = As + (4 + w) * 512;
  bf16* lB0 = Bs + w * 512;
  bf16* lB1 = Bs + (4 + w) * 512;

  for (int k0 = 0; k0 < D_; k0 += 32) {
    __syncthreads();
    gload16(gA0 + k0, lA0);
    gload16(gA1 + k0, lA1);
    gload16(gB0 + k0, lB0);
    gload16(gB1 + k0, lB1);
    __syncthreads();
    bf16x8 af[4], bb[4];
#pragma unroll
    for (int i = 0; i < 4; i++) {
      int rr = wm + i * 16 + rl;
      af[i] = *(const bf16x8*)(As + rr * 32 + (qq ^ ((rr >> 1) & 3)) * 8);
    }
#pragma unroll
    for (int j = 0; j < 4; j++) {
      int rr = wn + j * 16 + rl;
      bb[j] = *(const bf16x8*)(Bs + rr * 32 + (qq ^ ((rr >> 1) & 3)) * 8);
    }
#pragma unroll
    for (int i = 0; i < 4; i++)
#pragma unroll
      for (int j = 0; j < 4; j++)
        acc[i][j] = mfma16(af[i], bb[j], acc[i][j]);
  }
  C += (int64_t)z * D_ * D_;
#pragma unroll
  for (int j = 0; j < 4; j++) {
    int gn = n0 + wn + j * 16 + rl;
#pragma unroll
    for (int i = 0; i < 4; i++) {
      int gm0 = m0 + wm + i * 16 + qq * 4;
#pragma unroll
      for (int r2 = 0; r2 < 4; r2++)
        C[(int64_t)(gm0 + r2) * D_ + gn] = (bf16)acc[i][j][r2];
    }
  }
}

// ----------------- L3: 256^2-tile phase-split GEMM (kh + vhT) --------------
__global__ __launch_bounds__(512) void gemm256(
    const bf16* __restrict__ A,    // mkmv (z=0: mk, z=1: mv)
    const bf16* __restrict__ Wc,   // +D*D = Wc_k, +2D*D = Wc_v
    const float* __restrict__ bc,  // combined bias; +D = bik, +2D = biv
    bf16* __restrict__ kh, bf16* __restrict__ vhT,
    const bf16* __restrict__ qA, const bf16* __restrict__ qB,
    bf16* __restrict__ qC, const float* __restrict__ qbias) {
  extern __shared__ __align__(16) bf16 lds[];  // 4 * (8192 A + 8192 B) bf16
  const int bid = blockIdx.x;
  if (bid >= 256) {  // thin qh blocks at grid tail
    if (threadIdx.x < 256) {
      int n0q = (bid - 256) * 64;
      thin_gemm<2, 1024, bf16>(qA, D_, qB + (int64_t)n0q * D_, D_,
                               qC + n0q, D_, qbias + n0q, 0.125f);
    }
    return;
  }
  const int lin = bid;
  const int xcd = lin & 7, s = lin >> 3;
  const int z = xcd >> 2;
  const int m0 = ((xcd & 3) * 8 + (s >> 2)) * 256;
  const int n0 = (s & 3) * 256;
  const bf16* Ab = A + (int64_t)z * M_ * D_;
  const bf16* Bb = Wc + (int64_t)(z + 1) * D_ * D_;
  const float* bias = bc + (z + 1) * D_;

  const int tid = threadIdx.x, lane = tid & 63, w = tid >> 6;
  const int rl = lane & 15, qq = lane >> 4;
  const int wr = w >> 2, wcn = w & 3;

  const int ci0 = w * 128 + lane, ci1 = ci0 + 64;
  const int ra0 = ci0 >> 2, ca0 = (ci0 & 3) ^ ((ra0 >> 1) & 3);
  const int ra1 = ci1 >> 2, ca1 = (ci1 & 3) ^ ((ra1 >> 1) & 3);
  const bf16* gA0 = Ab + (int64_t)(m0 + ra0) * D_ + ca0 * 8;
  const bf16* gA1 = Ab + (int64_t)(m0 + ra1) * D_ + ca1 * 8;
  const bf16* gB0 = Bb + (int64_t)(n0 + ra0) * D_ + ca0 * 8;
  const bf16* gB1 = Bb + (int64_t)(n0 + ra1) * D_ + ca1 * 8;
  const int lA0 = w * 1024, lA1 = lA0 + 512;

  f32x4 acc[8][4] = {};
  bf16x8 bfr[4], afr[4];
  const int sq8 = (qq ^ ((rl >> 1) & 3)) * 8;

#define SCB __builtin_amdgcn_sched_barrier(0)
#define BARR __builtin_amdgcn_s_barrier()
#define VMW(N) asm volatile("s_waitcnt vmcnt(" #N ")")

#define STAGE_FULL(BUF, KT)                          \
  do {                                               \
    bf16* bse_ = lds + (BUF) * 16384;                \
    gload16(gA0 + (KT) * 32, bse_ + lA0);            \
    gload16(gA1 + (KT) * 32, bse_ + lA1);            \
    gload16(gB0 + (KT) * 32, bse_ + 8192 + lA0);     \
    gload16(gB1 + (KT) * 32, bse_ + 8192 + lA1);     \
  } while (0)

#define PH_A(BUF, DOSTAGE, SKT)                                              \
  do {                                                                       \
    const bf16* ba_ = lds + (BUF) * 16384;                                   \
    const bf16* bb_ = ba_ + 8192;                                            \
    for (int j = 0; j < 4; j++)                                              \
      bfr[j] = *(const bf16x8*)(bb_ + (wcn * 64 + j * 16 + rl) * 32 + sq8);  \
    for (int mi = 0; mi < 4; mi++)                                           \
      afr[mi] = *(const bf16x8*)(ba_ + (wr * 128 + mi * 16 + rl) * 32 + sq8);\
    if (DOSTAGE) {                                                           \
      bf16* bse_ = lds + ((SKT) & 3) * 16384;                                \
      gload16(gA0 + (SKT) * 32, bse_ + lA0);                                 \
      gload16(gA1 + (SKT) * 32, bse_ + lA1);                                 \
    }                                                                        \
    SCB; BARR; SCB;                                                          \
    __builtin_amdgcn_s_setprio(1);                                           \
    for (int mi = 0; mi < 4; mi++)                                           \
      for (int j = 0; j < 4; j++)                                            \
        acc[mi][j] = mfma16(afr[mi], bfr[j], acc[mi][j]);                    \
    __builtin_amdgcn_s_setprio(0);                                           \
    SCB; BARR; SCB;                                                          \
  } while (0)

#define PH_B(BUF, DOSTAGE, SKT, VMSTMT)                                      \
  do {                                                                       \
    const bf16* ba_ = lds + (BUF) * 16384;                                   \
    for (int mi = 0; mi < 4; mi++)                                           \
      afr[mi] =                                                              \
          *(const bf16x8*)(ba_ + (wr * 128 + (mi + 4) * 16 + rl) * 32 + sq8);\
    if (DOSTAGE) {                                                           \
      bf16* bse_ = lds + ((SKT) & 3) * 16384;                                \
      gload16(gB0 + (SKT) * 32, bse_ + 8192 + lA0);                          \
      gload16(gB1 + (SKT) * 32, bse_ + 8192 + lA1);                          \
    }                                                                        \
    VMSTMT;                                                                  \
    SCB; BARR; SCB;                                                          \
    __builtin_amdgcn_s_setprio(1);                                           \
    for (int mi = 0; mi < 4; mi++)                                           \
      for (int j = 0; j < 4; j++)                                            \
        acc[mi + 4][j] = mfma16(afr[mi], bfr[j], acc[mi + 4][j]);            \
    __builtin_amdgcn_s_setprio(0);                                           \
    SCB; BARR; SCB;                                                          \
  } while (0)

  STAGE_FULL(0, 0);
  STAGE_FULL(1, 1);
  STAGE_FULL(2, 2);
  VMW(8);
  SCB; BARR; SCB;

#pragma unroll 1
  for (int t = 0; t < 7; t++) {
    const int kb = t * 4;
    PH_A(0, 1, kb + 3); PH_B(0, 1, kb + 3, VMW(8));
    PH_A(1, 1, kb + 4); PH_B(1, 1, kb + 4, VMW(8));
    PH_A(2, 1, kb + 5); PH_B(2, 1, kb + 5, VMW(8));
    PH_A(3, 1, kb + 6); PH_B(3, 1, kb + 6, VMW(8));
  }
  PH_A(0, 1, 31); PH_B(0, 1, 31, VMW(8));
  PH_A(1, 0, 0);  PH_B(1, 0, 0, VMW(4));
  PH_A(2, 0, 0);  PH_B(2, 0, 0, VMW(0));
  PH_A(3, 0, 0);  PH_B(3, 0, 0, (void)0);

#undef SCB
#undef BARR
#undef VMW
#undef STAGE_FULL
#undef PH_A
#undef PH_B

  if (z == 0) {
#pragma unroll
    for (int j = 0; j < 4; j++) {
      int gn = n0 + wcn * 64 + j * 16 + rl;
      float bb2 = bias[gn];
#pragma unroll
      for (int mi = 0; mi < 8; mi++) {
        int gm0 = m0 + wr * 128 + mi * 16 + qq * 4;
#pragma unroll
        for (int r = 0; r < 4; r++)
          kh[(int64_t)(gm0 + r) * D_ + gn] = (bf16)(acc[mi][j][r] + bb2);
      }
    }
  } else {
#pragma unroll
    for (int j = 0; j < 4; j++) {
      int gn = n0 + wcn * 64 + j * 16 + rl;
      float bb2 = bias[gn];
#pragma unroll
      for (int mi = 0; mi < 8; mi++) {
        int gm0 = m0 + wr * 128 + mi * 16 + qq * 4;
        f32x4 a = acc[mi][j];
        bf16x4 o = { (bf16)(a[0] + bb2), (bf16)(a[1] + bb2),
                     (bf16)(a[2] + bb2), (bf16)(a[3] + bb2) };
        *(bf16x4*)(vhT + (int64_t)gn * M_ + gm0) = o;
      }
    }
  }
}

// --------------------------- flash r2, no-max (L4) -------------------------
// 512 blocks: h (16) x key-chunk c (32, 256 keys) => 2 blocks/CU co-resident
// (launch_bounds(256,2), LDS 9KB) = 2 waves/SIMD. The serial chain
// (loads -> QK MFMA -> exp -> LDS P -> PV MFMA) now has cross-wave overlap.
__global__ __launch_bounds__(256, 2) void flash_kernel(
    const bf16* __restrict__ qh, const bf16* __restrict__ kh,
    const bf16* __restrict__ vhT, float* __restrict__ Oraw,
    float* __restrict__ lmat) {
  const int tid = threadIdx.x, lane = tid & 63, w = tid >> 6;
  const int rl = lane & 15, qq = lane >> 4;
  const int h = blockIdx.x >> 5, c = blockIdx.x & 31;
  __shared__ alignas(16) bf16 Plds[4 * 16 * 72];
  const bf16* qhp = qh + (int64_t)(w * 16 + rl) * D_ + h * 64 + qq * 8;
  bf16x8 aq0 = *(const bf16x8*)(qhp);
  bf16x8 aq1 = *(const bf16x8*)(qhp + 32);
  float lsum[4] = {0.f, 0.f, 0.f, 0.f};
  f32x4 acc_o[4] = {};
  bf16* pl = Plds + w * 1152;
  const bf16* khb = kh + (int64_t)(c * 256) * D_ + h * 64 + qq * 8;
  const bf16* vtb = vhT + (int64_t)(h * 64) * M_ + c * 256 + qq * 8;
  for (int nt = 0; nt < 4; nt++) {
    int mb = nt * 64;
    bf16x8 bk0[4], bk1[4], vv0[4], vv1[4];
#pragma unroll
    for (int j = 0; j < 4; j++) {
      const bf16* p = khb + (int64_t)(mb + j * 16 + rl) * D_;
      bk0[j] = *(const bf16x8*)(p);
      bk1[j] = *(const bf16x8*)(p + 32);
      const bf16* q = vtb + (int64_t)(j * 16 + rl) * M_ + mb;
      vv0[j] = *(const bf16x8*)(q);
      vv1[j] = *(const bf16x8*)(q + 32);
    }
    f32x4 s[4] = {};
#pragma unroll
    for (int j = 0; j < 4; j++) {
      s[j] = mfma16(aq0, bk0[j], s[j]);
      s[j] = mfma16(aq1, bk1[j], s[j]);
    }
#pragma unroll
    for (int j = 0; j < 4; j++)
#pragma unroll
      for (int r = 0; r < 4; r++) {
        float p = __expf(s[j][r]);
        lsum[r] += p;
        pl[(qq * 4 + r) * 72 + j * 16 + rl] = (bf16)p;
      }
    bf16x8 pa0 = *(const bf16x8*)(pl + rl * 72 + qq * 8);
    bf16x8 pa1 = *(const bf16x8*)(pl + rl * 72 + 32 + qq * 8);
#pragma unroll
    for (int j = 0; j < 4; j++) {
      acc_o[j] = mfma16(pa0, vv0[j], acc_o[j]);
      acc_o[j] = mfma16(pa1, vv1[j], acc_o[j]);
    }
  }
#pragma unroll
  for (int msk = 1; msk <= 8; msk <<= 1)
#pragma unroll
    for (int r = 0; r < 4; r++) lsum[r] += __shfl_xor(lsum[r], msk, 64);
#pragma unroll
  for (int j = 0; j < 4; j++)
#pragma unroll
    for (int r = 0; r < 4; r++)
      atomicAdd(&Oraw[(int64_t)(w * 16 + qq * 4 + r) * D_ + h * 64 + j * 16 + rl],
                acc_o[j][r]);
  if (rl == 0)
#pragma unroll
    for (int r = 0; r < 4; r++)
      atomicAdd(&lmat[h * 64 + w * 16 + qq * 4 + r], lsum[r]);
}

// ----------------------- split-K atomic tail stage -------------------------
// KIND: 0=bf16; 1=fp32; 2=relu(fp32); 3=sigmoid(p0)*p1; 4=p0*(1/l[h][m]).
struct Chunk { const void* p0; const void* p1; int ld; int kind; };
struct StageArgs { Chunk c[16]; };

template <int NKK>
__global__ __launch_bounds__(256) void tail_stage(
    StageArgs sa, const bf16* __restrict__ Bw, int ldb,
    float* __restrict__ Craw, int ldc) {
  const int n0 = blockIdx.x * 64, kc = blockIdx.y;
  const int bk0 = kc * NKK * 32;
  const Chunk ch = sa.c[kc];
  const int tid = threadIdx.x, lane = tid & 63, w = tid >> 6;
  const int rl = lane & 15, qq = lane >> 4;
  const int m = w * 16 + rl;
  const bf16* pb[4];
#pragma unroll
  for (int j = 0; j < 4; j++)
    pb[j] = Bw + (int64_t)(n0 + j * 16 + rl) * ldb + bk0 + qq * 8;
  f32x4 acc[4] = {};
#pragma unroll
  for (int kk = 0; kk < NKK; kk++) {
    bf16x8 af;
    if (ch.kind == 0) {
      af = *(const bf16x8*)((const bf16*)ch.p0 + (int64_t)m * ch.ld +
                            kk * 32 + qq * 8);
    } else {
      const float* p = (const float*)ch.p0 + (int64_t)m * ch.ld + kk * 32 + qq * 8;
      float4 u0 = *(const float4*)p;
      float4 u1 = *(const float4*)(p + 4);
      if (ch.kind == 2) {
        u0.x = fmaxf(u0.x, 0.f); u0.y = fmaxf(u0.y, 0.f);
        u0.z = fmaxf(u0.z, 0.f); u0.w = fmaxf(u0.w, 0.f);
        u1.x = fmaxf(u1.x, 0.f); u1.y = fmaxf(u1.y, 0.f);
        u1.z = fmaxf(u1.z, 0.f); u1.w = fmaxf(u1.w, 0.f);
      } else if (ch.kind == 3) {
        const float* pm = (const float*)ch.p1 + (int64_t)m * ch.ld + kk * 32 + qq * 8;
        float4 m0 = *(const float4*)pm;
        float4 m1 = *(const float4*)(pm + 4);
        u0.x = m0.x / (1.f + __expf(-u0.x)); u0.y = m0.y / (1.f + __expf(-u0.y));
        u0.z = m0.z / (1.f + __expf(-u0.z)); u0.w = m0.w / (1.f + __expf(-u0.w));
        u1.x = m1.x / (1.f + __expf(-u1.x)); u1.y = m1.y / (1.f + __expf(-u1.y));
        u1.z = m1.z / (1.f + __expf(-u1.z)); u1.w = m1.w / (1.f + __expf(-u1.w));
      } else if (ch.kind == 4) {
        int hidx = (bk0 + kk * 32) >> 6;
        float linv = 1.0f / ((const float*)ch.p1)[hidx * 64 + m];
        u0.x *= linv; u0.y *= linv; u0.z *= linv; u0.w *= linv;
        u1.x *= linv; u1.y *= linv; u1.z *= linv; u1.w *= linv;
      }
      af = (bf16x8){ (bf16)u0.x, (bf16)u0.y, (bf16)u0.z, (bf16)u0.w,
                     (bf16)u1.x, (bf16)u1.y, (bf16)u1.z, (bf16)u1.w };
    }
    bf16x8 bf_[4];
#pragma unroll
    for (int j = 0; j < 4; j++) bf_[j] = *(const bf16x8*)(pb[j] + kk * 32);
#pragma unroll
    for (int j = 0; j < 4; j++) acc[j] = mfma16(af, bf_[j], acc[j]);
  }
#pragma unroll
  for (int j = 0; j < 4; j++) {
    int gn = n0 + j * 16 + rl;
#pragma unroll
    for (int r = 0; r < 4; r++) {
      int gm = w * 16 + qq * 4 + r;
      atomicAdd(&Craw[(int64_t)gm * ldc + gn], acc[j][r]);
    }
  }
}

// ------------------------------- launch ------------------------------------
extern "C" void kernel_launch(void* const* d_in, const int* in_sizes, int n_in,
                              void* d_out, int out_size, void* d_ws,
                              size_t ws_size, hipStream_t stream) {
  (void)in_sizes; (void)n_in; (void)out_size;
  const float* x    = (const float*)d_in[0];
  const float* mk   = (const float*)d_in[1];
  const float* mv   = (const float*)d_in[2];
  const float* Wq   = (const float*)d_in[3];
  const float* bq   = (const float*)d_in[4];
  const float* Wk   = (const float*)d_in[5];
  const float* bk   = (const float*)d_in[6];
  const float* Wv   = (const float*)d_in[7];
  const float* bv   = (const float*)d_in[8];
  const float* inw  = (const float*)d_in[9];
  const float* inb  = (const float*)d_in[10];
  const float* outw = (const float*)d_in[11];
  const float* outb = (const float*)d_in[12];
  const float* gW1  = (const float*)d_in[13];
  const float* gb1  = (const float*)d_in[14];
  const float* gW2  = (const float*)d_in[15];
  const float* gb2  = (const float*)d_in[16];
  const float* iW1  = (const float*)d_in[17];
  const float* ib1  = (const float*)d_in[18];
  const float* iW2  = (const float*)d_in[19];
  const float* ib2  = (const float*)d_in[20];

  char* ws = (char*)d_ws;
  size_t off = 0;
  auto alloc = [&](size_t bytes) {
    char* p = ws + off;
    off += (bytes + 255) & ~(size_t)255;
    return p;
  };
  bf16* mkmv  = (bf16*)alloc((size_t)2 * M_ * D_ * 2);
  bf16* inpj  = (bf16*)alloc((size_t)3 * D_ * D_ * 2);
  bf16* WT    = (bf16*)alloc((size_t)3 * D_ * D_ * 2);
  bf16* Wc    = (bf16*)alloc((size_t)3 * D_ * D_ * 2);
  float* bc   = (float*)alloc(3 * D_ * 4);
  bf16* xbf   = (bf16*)alloc((size_t)B_ * D_ * 2);
  bf16* qh    = (bf16*)alloc((size_t)B_ * D_ * 2);
  bf16* kh    = (bf16*)alloc((size_t)M_ * D_ * 2);
  bf16* vhT   = (bf16*)alloc((size_t)M_ * D_ * 2);
  float* Oraw = (float*)alloc((size_t)B_ * D_ * 4);
  float* lmat = (float*)alloc((size_t)H_ * B_ * 4);
  float* msR  = (float*)alloc((size_t)B_ * D_ * 4);
  float* g1R  = (float*)alloc((size_t)B_ * D_ * 4);
  float* gateR= (float*)alloc((size_t)B_ * D_ * 4);
  float* h1R  = (float*)alloc((size_t)B_ * 2 * D_ * 4);
  bf16* gW1b  = (bf16*)alloc((size_t)D_ * 2 * D_ * 2);
  bf16* gW2b  = (bf16*)alloc((size_t)D_ * D_ * 2);
  bf16* iW1b  = (bf16*)alloc((size_t)2 * D_ * 2 * D_ * 2);
  bf16* iW2b  = (bf16*)alloc((size_t)D_ * 2 * D_ * 2);
  bf16* outwb = (bf16*)alloc((size_t)D_ * D_ * 2);
  if (ws_size < off) return;

  // L1: prep-A (cvt ends in BLOCK units of 8192 floats)
  PrepArgs pa;
  pa.d[0] = { inw, inpj, 384 };
  pa.d[1] = { x,   xbf,  392 };
  pa.Wq = Wq; pa.Wk = Wk; pa.Wv = Wv; pa.inw = inw; pa.inb = inb;
  pa.bq = bq; pa.bk = bk; pa.bv = bv;
  pa.outb = outb; pa.gb1 = gb1; pa.gb2 = gb2; pa.ib1 = ib1; pa.ib2 = ib2;
  pa.WT = WT; pa.bc = bc; pa.msR = msR; pa.g1R = g1R; pa.gateR = gateR;
  pa.h1R = h1R; pa.out = (float*)d_out; pa.Oraw = Oraw; pa.lmat = lmat;
  prep_kernel<<<dim3(4680), 256, 0, stream>>>(pa);

  // L2': Wc GEMM (192 blocks first) + bulk cvt (3328 blocks)
  L2Args ca;
  ca.d[0] = { mk,   mkmv,           1024 };
  ca.d[1] = { mv,   mkmv + M_ * D_, 2048 };
  ca.d[2] = { gW1,  gW1b,           2304 };
  ca.d[3] = { gW2,  gW2b,           2432 };
  ca.d[4] = { iW1,  iW1b,           2944 };
  ca.d[5] = { iW2,  iW2b,           3200 };
  ca.d[6] = { outw, outwb,          3328 };
  gemm_bigc<<<dim3(3520), 256, 0, stream>>>(inpj, WT, Wc, ca);

  // L3: kh / vhT via phase-split 256^2 kernel (+ qh thin blocks at tail)
  hipFuncSetAttribute((const void*)gemm256,
                      hipFuncAttributeMaxDynamicSharedMemorySize, 131072);
  gemm256<<<dim3(272), dim3(512), 131072, stream>>>(
      mkmv, Wc, bc, kh, vhT, xbf, Wc, qh, bc);

  // L4: flash partials -> atomic Oraw / lmat (512 blocks = 2/CU)
  flash_kernel<<<dim3(512), 256, 0, stream>>>(qh, kh, vhT, Oraw, lmat);

  // L5 S1: msR += (Oraw/l) @ outwb^T   grid (16 n, 8 kc of 128)
  StageArgs s1;
  for (int kc = 0; kc < 8; kc++) s1.c[kc] = { Oraw + kc * 128, lmat, D_, 4 };
  tail_stage<4><<<dim3(16, 8), 256, 0, stream>>>(s1, outwb, D_, msR, D_);

  // L6 S2: g1R += [x | msR] @ gW1^T    grid (16, 16 kc of 128, K=2048)
  StageArgs s2;
  for (int kc = 0; kc < 8; kc++)  s2.c[kc] = { xbf + kc * 128, nullptr, D_, 0 };
  for (int kc = 8; kc < 16; kc++) s2.c[kc] = { msR + (kc - 8) * 128, nullptr, D_, 1 };
  tail_stage<4><<<dim3(16, 16), 256, 0, stream>>>(s2, gW1b, 2 * D_, g1R, D_);

  // L7 S3: gateR += relu(g1R) @ gW2^T  grid (16, 8)
  StageArgs s3;
  for (int kc = 0; kc < 8; kc++) s3.c[kc] = { g1R + kc * 128, nullptr, D_, 2 };
  tail_stage<4><<<dim3(16, 8), 256, 0, stream>>>(s3, gW2b, D_, gateR, D_);

  // L8 S4: h1R += [x | sig(gateR)*msR] @ iW1^T  grid (32, 16)
  StageArgs s4;
  for (int kc = 0; kc < 8; kc++)  s4.c[kc] = { xbf + kc * 128, nullptr, D_, 0 };
  for (int kc = 8; kc < 16; kc++)
    s4.c[kc] = { gateR + (kc - 8) * 128, msR + (kc - 8) * 128, D_, 3 };
  tail_stage<4><<<dim3(32, 16), 256, 0, stream>>>(s4, iW1b, 2 * D_, h1R, 2 * D_);

  // L9 S5: out += relu(h1R) @ iW2^T    grid (16, 16, K=2048)
  StageArgs s5;
  for (int kc = 0; kc < 16; kc++) s5.c[kc] = { h1R + kc * 128, nullptr, 2 * D_, 2 };
  tail_stage<4><<<dim3(16, 16), 256, 0, stream>>>(s5, iW2b, 2 * D_,
                                                  (float*)d_out, D_);
}